// Round 2
// baseline (1313.089 us; speedup 1.0000x reference)
//
#include <hip/hip_runtime.h>
#include <math.h>

#define GG 32
#define NN1 1024
#define FF 128
#define MAT (NN1*NN1)
#define KKEEP 32768
#define NBINS 4096
#define CAP 8192
#define TIECAP 64
#define BINLO 1311
#define BINHI 1760

typedef __attribute__((ext_vector_type(8))) short short8;
typedef __attribute__((ext_vector_type(4))) float floatx4;
typedef __attribute__((ext_vector_type(8))) unsigned short ushort8;

__device__ __forceinline__ int fbin(float v) {
    int b = (int)((v - 0.95f) * 81920.0f);
    b = b < 0 ? 0 : (b > NBINS - 1 ? NBINS - 1 : b);
    return b;
}
__device__ __forceinline__ unsigned short f2bf(float f) {
    union { float f; unsigned u; } x; x.f = f;
    unsigned r = x.u + 0x7fffu + ((x.u >> 16) & 1u);
    return (unsigned short)(r >> 16);
}
__device__ __forceinline__ float bf2f(unsigned short h) {
    union { unsigned u; float f; } x; x.u = ((unsigned)h) << 16;
    return x.f;
}
__device__ __forceinline__ float gelu(float v) {
    return 0.5f * v * (1.0f + erff(v * 0.70710678118654752f));
}

// ---- K1: fused fine-histogram [0.95,1.0) + candidate gather (bins BINLO..BINHI) ----
__global__ __launch_bounds__(256) void k_histgather(const float* __restrict__ adj,
                                                    unsigned* __restrict__ hist,
                                                    uint2* __restrict__ cand,
                                                    unsigned* __restrict__ candCount) {
    __shared__ unsigned lh[NBINS];
    int g = blockIdx.x >> 4, seg = blockIdx.x & 15;
    for (int i = threadIdx.x; i < NBINS; i += 256) lh[i] = 0;
    __syncthreads();
    const float4* p = (const float4*)(adj + (size_t)g * MAT + (size_t)seg * 65536);
    uint2* cg = cand + (size_t)g * CAP;
    for (int i = threadIdx.x; i < 16384; i += 256) {
        float4 v = p[i];
        unsigned base = (unsigned)(seg * 65536 + i * 4);
        float vv[4] = {v.x, v.y, v.z, v.w};
#pragma unroll
        for (int d = 0; d < 4; ++d) {
            if (vv[d] >= 0.95f) {
                int b = fbin(vv[d]);
                atomicAdd(&lh[b], 1u);
                if (b >= BINLO && b <= BINHI) {
                    unsigned pos = atomicAdd(&candCount[g], 1u);
                    if (pos < CAP) {
                        cg[pos].x = __float_as_uint(vv[d]);
                        cg[pos].y = base + (unsigned)d;
                    }
                }
            }
        }
    }
    __syncthreads();
    unsigned* gh = hist + g * NBINS;
    for (int i = threadIdx.x; i < NBINS; i += 256)
        if (lh[i]) atomicAdd(&gh[i], lh[i]);
}

// ---- K2: threshold bin + needed count inside it ----
__global__ __launch_bounds__(256) void k_selbin(const unsigned* __restrict__ hist,
                                                unsigned* __restrict__ binSel,
                                                unsigned* __restrict__ needArr) {
    int g = blockIdx.x;
    __shared__ unsigned csum[256];
    __shared__ unsigned after[256];
    const unsigned* gh = hist + g * NBINS;
    int t = threadIdx.x;
    unsigned s = 0;
    for (int i = 0; i < 16; ++i) s += gh[t * 16 + i];
    csum[t] = s;
    __syncthreads();
    if (t == 0) {
        unsigned run = 0;
        for (int c = 255; c >= 0; --c) { after[c] = run; run += csum[c]; }
    }
    __syncthreads();
    if (after[t] < (unsigned)KKEEP && after[t] + csum[t] >= (unsigned)KKEEP) {
        unsigned cum = after[t];
        for (int b2 = t * 16 + 15; b2 >= t * 16; --b2) {
            unsigned h = gh[b2];
            cum += h;
            if (cum >= (unsigned)KKEEP) {
                binSel[g] = (unsigned)b2;
                needArr[g] = (unsigned)KKEEP - (cum - h);
                break;
            }
        }
    }
}

// ---- K3: exact rank within threshold bin -> T + tie index list ----
__global__ __launch_bounds__(256) void k_rank(const uint2* __restrict__ cand,
                                              const unsigned* __restrict__ candCount,
                                              const unsigned* __restrict__ binSel,
                                              const unsigned* __restrict__ needArr,
                                              float* __restrict__ thr,
                                              unsigned* __restrict__ tieIdx,
                                              unsigned* __restrict__ tieCount) {
    int g = blockIdx.x;
    __shared__ uint2 mem[256];
    __shared__ unsigned mb;
    __shared__ float sT;
    unsigned m = candCount[g]; if (m > CAP) m = CAP;
    unsigned bsel = binSel[g];
    unsigned need = needArr[g];
    const uint2* cg = cand + (size_t)g * CAP;
    int t = threadIdx.x;
    if (t == 0) mb = 0;
    __syncthreads();
    for (unsigned ci = t; ci < m; ci += 256) {
        float v = __uint_as_float(cg[ci].x);
        if ((unsigned)fbin(v) == bsel) {
            unsigned i = atomicAdd(&mb, 1u);
            if (i < 256) mem[i] = cg[ci];
        }
    }
    __syncthreads();
    unsigned M = mb; if (M > 256) M = 256;
    unsigned rk = 0; float v = 0.f; unsigned idx = 0;
    if (t < (int)M) {
        v = __uint_as_float(mem[t].x);
        idx = mem[t].y;
        for (unsigned j = 0; j < M; ++j) {
            float vj = __uint_as_float(mem[j].x);
            if (vj > v || (vj == v && mem[j].y < idx)) ++rk;
        }
        if (rk == need - 1) sT = v;
    }
    __syncthreads();
    float T = sT;
    if (t == 0) thr[g] = T;
    if (t < (int)M && v == T && rk < need) {
        unsigned pos = atomicAdd(&tieCount[g], 1u);
        if (pos < TIECAP) tieIdx[g * TIECAP + pos] = idx;
    }
}

__device__ __forceinline__ float keepf(float v, unsigned idx, float T,
                                       const unsigned* __restrict__ tie, unsigned tc) {
    if (v > T) return v;
    if (v == T) {
        for (unsigned i = 0; i < tc; ++i)
            if (tie[i] == idx) return v;
    }
    return 0.f;
}

// ---- K4: masked symmetrize into d_out adj region + deg ----
__global__ __launch_bounds__(256) void k_sym(const float* __restrict__ adj,
                                             const float* __restrict__ thr,
                                             const unsigned* __restrict__ tieIdx,
                                             const unsigned* __restrict__ tieCount,
                                             float* __restrict__ sOut,
                                             float* __restrict__ deg) {
    __shared__ float Al[64 * 65];
    __shared__ float Bl[64 * 65];
    int g = blockIdx.x / 136;
    int pr = blockIdx.x % 136;
    int ti = 0, rem = pr;
    while (rem >= 16 - ti) { rem -= 16 - ti; ++ti; }
    int tj = ti + rem;
    int t = threadIdx.x;
    float T = thr[g];
    unsigned tc = tieCount[g];
    if (tc > TIECAP) tc = TIECAP;
    const unsigned* tie = tieIdx + g * TIECAP;
    const float* ag = adj + (size_t)g * MAT;
    float* sg = sOut + (size_t)g * MAT;
    float* dg = deg + g * NN1;
    int r0 = t >> 4;
    int c0 = (t & 15) << 2;
    int i0 = ti << 6, j0 = tj << 6;
    bool off = (ti != tj);
    float av[4][4], bv[4][4];
#pragma unroll
    for (int q = 0; q < 4; ++q) {
        int r = r0 + (q << 4);
        unsigned base = (unsigned)((i0 + r) * NN1 + j0 + c0);
        float4 v = *(const float4*)(ag + base);
        av[q][0] = keepf(v.x, base + 0, T, tie, tc);
        av[q][1] = keepf(v.y, base + 1, T, tie, tc);
        av[q][2] = keepf(v.z, base + 2, T, tie, tc);
        av[q][3] = keepf(v.w, base + 3, T, tie, tc);
        Al[r * 65 + c0 + 0] = av[q][0];
        Al[r * 65 + c0 + 1] = av[q][1];
        Al[r * 65 + c0 + 2] = av[q][2];
        Al[r * 65 + c0 + 3] = av[q][3];
    }
    if (off) {
#pragma unroll
        for (int q = 0; q < 4; ++q) {
            int r = r0 + (q << 4);
            unsigned base = (unsigned)((j0 + r) * NN1 + i0 + c0);
            float4 v = *(const float4*)(ag + base);
            bv[q][0] = keepf(v.x, base + 0, T, tie, tc);
            bv[q][1] = keepf(v.y, base + 1, T, tie, tc);
            bv[q][2] = keepf(v.z, base + 2, T, tie, tc);
            bv[q][3] = keepf(v.w, base + 3, T, tie, tc);
            Bl[r * 65 + c0 + 0] = bv[q][0];
            Bl[r * 65 + c0 + 1] = bv[q][1];
            Bl[r * 65 + c0 + 2] = bv[q][2];
            Bl[r * 65 + c0 + 3] = bv[q][3];
        }
    }
    __syncthreads();
#pragma unroll
    for (int q = 0; q < 4; ++q) {
        int r = r0 + (q << 4);
        const float* Tr = off ? Bl : Al;
        float s0 = 0.5f * (av[q][0] + Tr[(c0 + 0) * 65 + r]);
        float s1 = 0.5f * (av[q][1] + Tr[(c0 + 1) * 65 + r]);
        float s2 = 0.5f * (av[q][2] + Tr[(c0 + 2) * 65 + r]);
        float s3 = 0.5f * (av[q][3] + Tr[(c0 + 3) * 65 + r]);
        *(float4*)(sg + (size_t)(i0 + r) * NN1 + j0 + c0) = make_float4(s0, s1, s2, s3);
        float rs = s0 + s1 + s2 + s3;
        rs += __shfl_xor(rs, 1);
        rs += __shfl_xor(rs, 2);
        rs += __shfl_xor(rs, 4);
        rs += __shfl_xor(rs, 8);
        if ((t & 15) == 0) atomicAdd(&dg[i0 + r], rs);
    }
    if (off) {
#pragma unroll
        for (int q = 0; q < 4; ++q) {
            int r = r0 + (q << 4);
            float s0 = 0.5f * (bv[q][0] + Al[(c0 + 0) * 65 + r]);
            float s1 = 0.5f * (bv[q][1] + Al[(c0 + 1) * 65 + r]);
            float s2 = 0.5f * (bv[q][2] + Al[(c0 + 2) * 65 + r]);
            float s3 = 0.5f * (bv[q][3] + Al[(c0 + 3) * 65 + r]);
            *(float4*)(sg + (size_t)(j0 + r) * NN1 + i0 + c0) = make_float4(s0, s1, s2, s3);
            float rs = s0 + s1 + s2 + s3;
            rs += __shfl_xor(rs, 1);
            rs += __shfl_xor(rs, 2);
            rs += __shfl_xor(rs, 4);
            rs += __shfl_xor(rs, 8);
            if ((t & 15) == 0) atomicAdd(&dg[j0 + r], rs);
        }
    }
}

// ---- K5: dinv ----
__global__ __launch_bounds__(256) void k_dinv(const float* __restrict__ deg,
                                              float* __restrict__ dinv) {
    int i = blockIdx.x * 256 + threadIdx.x;
    float d = deg[i];
    dinv[i] = (d > 0.f) ? (float)(1.0 / sqrt((double)d)) : 0.f;
}

// ---- K6: y = x @ W, stored transposed (k-major) as bf16 hi/lo splits ----
// Yh/Yl layout: [G][128 c][1024 k]
__global__ __launch_bounds__(256) void k_y(const float* __restrict__ x,
                                           const float* __restrict__ W,
                                           unsigned short* __restrict__ Yh,
                                           unsigned short* __restrict__ Yl) {
    __shared__ float Xl[64 * 128];
    int bx = blockIdx.x;
    int g = bx & 31, chunk = bx >> 5;
    int r0 = chunk * 64;
    int t = threadIdx.x;
    const float* xg = x + ((size_t)g * NN1 + r0) * FF;
    for (int i = t; i < 2048; i += 256) ((float4*)Xl)[i] = ((const float4*)xg)[i];
    __syncthreads();
    int Rr = (t >> 5) * 8;          // 8 rows per thread
    int c4 = (t & 31) * 4;          // 4 cols per thread
    float acc[8][4];
#pragma unroll
    for (int i = 0; i < 8; ++i)
#pragma unroll
        for (int j = 0; j < 4; ++j) acc[i][j] = 0.f;
    for (int f = 0; f < 128; ++f) {
        float4 wv = *(const float4*)(W + (size_t)f * 128 + c4);
#pragma unroll
        for (int i = 0; i < 8; ++i) {
            float a = Xl[(Rr + i) * 128 + f];
            acc[i][0] += a * wv.x;
            acc[i][1] += a * wv.y;
            acc[i][2] += a * wv.z;
            acc[i][3] += a * wv.w;
        }
    }
#pragma unroll
    for (int cc = 0; cc < 4; ++cc) {
        int c = c4 + cc;
        size_t base = ((size_t)g * 128 + c) * NN1 + r0 + Rr;
        ushort8 hh, ll;
#pragma unroll
        for (int i = 0; i < 8; ++i) {
            float v = acc[i][cc];
            unsigned short h = f2bf(v);
            hh[i] = h;
            ll[i] = f2bf(v - bf2f(h));
        }
        *(ushort8*)(Yh + base) = hh;
        *(ushort8*)(Yl + base) = ll;
    }
}

// ---- K7: fused dinv-scale (norm write-back in place) + split-bf16 MFMA GEMM +
//          epilogue h = gelu(y + A_n y + b). 32-row panels, grid 1024, 4 waves. ----
__global__ __launch_bounds__(256) void k_ng1(const unsigned short* __restrict__ Yh,
                                             const unsigned short* __restrict__ Yl,
                                             const float* __restrict__ dinv,
                                             float* __restrict__ sadj,
                                             const float* __restrict__ bias,
                                             float* __restrict__ hout) {
    __shared__ unsigned short AhL[32 * 40];
    __shared__ unsigned short AlL[32 * 40];
    int bx = blockIdx.x;
    int g = bx & 31, panel = bx >> 5;     // same-g blocks share XCD (bx%8 == g%8)
    int r0 = panel * 32;
    int t = threadIdx.x;
    int w = t >> 6, lane = t & 63;
    int q = lane >> 4, n16 = lane & 15;
    float* sg = sadj + (size_t)g * MAT;
    const float* dv = dinv + g * NN1;
    int srow = t >> 3, skc = (t & 7) << 2;     // staging: 32 rows x 32 k
    float drow = dv[r0 + srow];
    int cbase = w * 32;
    const unsigned short* yhg = Yh + (size_t)g * 128 * NN1;
    const unsigned short* ylg = Yl + (size_t)g * 128 * NN1;
    const unsigned short* ybh[2], *ybl[2];
#pragma unroll
    for (int ct = 0; ct < 2; ++ct) {
        size_t co = (size_t)(cbase + 16 * ct + n16) * NN1;
        ybh[ct] = yhg + co;
        ybl[ct] = ylg + co;
    }
    floatx4 acc[2][2];
#pragma unroll
    for (int i = 0; i < 2; ++i)
#pragma unroll
        for (int j = 0; j < 2; ++j) acc[i][j] = (floatx4){0.f, 0.f, 0.f, 0.f};

    for (int kt = 0; kt < 32; ++kt) {
        int k0 = kt << 5;
        // stage + scale + norm write-back + split
        float4 dj = *(const float4*)(dv + k0 + skc);
        float* ap = sg + (size_t)(r0 + srow) * NN1 + k0 + skc;
        float4 v = *(const float4*)ap;
        v.x *= drow * dj.x; v.y *= drow * dj.y;
        v.z *= drow * dj.z; v.w *= drow * dj.w;
        *(float4*)ap = v;
        float vv[4] = {v.x, v.y, v.z, v.w};
        ushort4 hh, ll;
        unsigned short* hp = (unsigned short*)&hh;
        unsigned short* lp = (unsigned short*)&ll;
#pragma unroll
        for (int d = 0; d < 4; ++d) {
            unsigned short h = f2bf(vv[d]);
            hp[d] = h;
            lp[d] = f2bf(vv[d] - bf2f(h));
        }
        *(ushort4*)(&AhL[srow * 40 + skc]) = hh;
        *(ushort4*)(&AlL[srow * 40 + skc]) = ll;
        __syncthreads();
        short8 ah[2], al[2], bh[2], bl[2];
#pragma unroll
        for (int rt = 0; rt < 2; ++rt) {
            ah[rt] = *(const short8*)(&AhL[(16 * rt + n16) * 40 + q * 8]);
            al[rt] = *(const short8*)(&AlL[(16 * rt + n16) * 40 + q * 8]);
        }
#pragma unroll
        for (int ct = 0; ct < 2; ++ct) {
            bh[ct] = *(const short8*)(ybh[ct] + k0 + q * 8);
            bl[ct] = *(const short8*)(ybl[ct] + k0 + q * 8);
        }
#pragma unroll
        for (int rt = 0; rt < 2; ++rt)
#pragma unroll
            for (int ct = 0; ct < 2; ++ct) {
                acc[rt][ct] = __builtin_amdgcn_mfma_f32_16x16x32_bf16(ah[rt], bh[ct], acc[rt][ct], 0, 0, 0);
                acc[rt][ct] = __builtin_amdgcn_mfma_f32_16x16x32_bf16(ah[rt], bl[ct], acc[rt][ct], 0, 0, 0);
                acc[rt][ct] = __builtin_amdgcn_mfma_f32_16x16x32_bf16(al[rt], bh[ct], acc[rt][ct], 0, 0, 0);
            }
        __syncthreads();
    }
    // epilogue: h = gelu(y + agg + b)
    float* hg = hout + (size_t)g * NN1 * FF;
#pragma unroll
    for (int rt = 0; rt < 2; ++rt)
#pragma unroll
        for (int ct = 0; ct < 2; ++ct) {
            int c = cbase + 16 * ct + n16;
            float bb = bias[c];
#pragma unroll
            for (int reg = 0; reg < 4; ++reg) {
                int r = r0 + 16 * rt + 4 * q + reg;
                float yv = bf2f(ybh[ct][r]) + bf2f(ybl[ct][r]);
                float val = acc[rt][ct][reg] + yv + bb;
                hg[(size_t)r * FF + c] = gelu(val);
            }
        }
}

extern "C" void kernel_launch(void* const* d_in, const int* in_sizes, int n_in,
                              void* d_out, int out_size, void* d_ws, size_t ws_size,
                              hipStream_t stream) {
    const float* x = (const float*)d_in[0];
    const float* adj = (const float*)d_in[1];
    const float* W = (const float*)d_in[2];
    const float* b = (const float*)d_in[3];
    float* out = (float*)d_out;
    float* hout = out;                            // [G*N, 128]
    float* adjn = out + (size_t)GG * NN1 * FF;    // [G, N, N]

    char* ws = (char*)d_ws;
    unsigned* hist      = (unsigned*)(ws);                 // 524288
    unsigned* candCount = (unsigned*)(ws + 524288);        // 128
    unsigned* tieCount  = (unsigned*)(ws + 524416);        // 128
    float*    deg       = (float*)(ws + 524544);           // 131072 -> 655616
    unsigned* binSel    = (unsigned*)(ws + 655616);        // 128
    unsigned* needArr   = (unsigned*)(ws + 655744);        // 128
    float*    thr       = (float*)(ws + 655872);           // 128
    unsigned* tieIdx    = (unsigned*)(ws + 656000);        // 8192 -> 664192
    uint2*    cand      = (uint2*)(ws + 664192);           // 2097152 -> 2761344
    float*    dinv      = (float*)(ws + 2761344);          // 131072 -> 2892416
    unsigned short* Yh  = (unsigned short*)(ws + 2892416); // 8388608 -> 11281024
    unsigned short* Yl  = (unsigned short*)(ws + 11281024);// 8388608 -> 19669632

    hipMemsetAsync(d_ws, 0, 655616, stream);   // hist + counts + deg

    k_histgather<<<512, 256, 0, stream>>>(adj, hist, cand, candCount);
    k_selbin<<<32, 256, 0, stream>>>(hist, binSel, needArr);
    k_rank<<<32, 256, 0, stream>>>(cand, candCount, binSel, needArr, thr, tieIdx, tieCount);
    k_sym<<<GG * 136, 256, 0, stream>>>(adj, thr, tieIdx, tieCount, adjn, deg);
    k_dinv<<<128, 256, 0, stream>>>(deg, dinv);
    k_y<<<512, 256, 0, stream>>>(x, W, Yh, Yl);
    k_ng1<<<1024, 256, 0, stream>>>(Yh, Yl, dinv, adjn, b, hout);
}

// Round 3
// 492.171 us; speedup vs baseline: 2.6680x; 2.6680x over previous
//
#include <hip/hip_runtime.h>
#include <math.h>

#define GG 32
#define NN1 1024
#define FF 128
#define MAT (NN1*NN1)
#define KKEEP 32768
#define NBINS 4096
#define CAP 8192
#define LCAP 1024
#define TIECAP 64
#define BINLO 1311
#define BINHI 1760

typedef __attribute__((ext_vector_type(8))) short short8;
typedef __attribute__((ext_vector_type(4))) float floatx4;
typedef __attribute__((ext_vector_type(8))) unsigned short ushort8;

__device__ __forceinline__ int fbin(float v) {
    int b = (int)((v - 0.95f) * 81920.0f);
    b = b < 0 ? 0 : (b > NBINS - 1 ? NBINS - 1 : b);
    return b;
}
__device__ __forceinline__ unsigned short f2bf(float f) {
    union { float f; unsigned u; } x; x.f = f;
    unsigned r = x.u + 0x7fffu + ((x.u >> 16) & 1u);
    return (unsigned short)(r >> 16);
}
__device__ __forceinline__ float bf2f(unsigned short h) {
    union { unsigned u; float f; } x; x.u = ((unsigned)h) << 16;
    return x.f;
}
__device__ __forceinline__ float gelu(float v) {
    return 0.5f * v * (1.0f + erff(v * 0.70710678118654752f));
}

// ---- K1: fused fine-histogram [0.95,1.0) + candidate gather (bins BINLO..BINHI)
//      candidates buffered in LDS; ONE global atomic per block ----
__global__ __launch_bounds__(256) void k_histgather(const float* __restrict__ adj,
                                                    unsigned* __restrict__ hist,
                                                    uint2* __restrict__ cand,
                                                    unsigned* __restrict__ candCount) {
    __shared__ unsigned lh[NBINS];
    __shared__ uint2 lcand[LCAP];
    __shared__ unsigned lcnt;
    __shared__ unsigned gbase;
    int g = blockIdx.x >> 4, seg = blockIdx.x & 15;
    for (int i = threadIdx.x; i < NBINS; i += 256) lh[i] = 0;
    if (threadIdx.x == 0) lcnt = 0;
    __syncthreads();
    const float4* p = (const float4*)(adj + (size_t)g * MAT + (size_t)seg * 65536);
    for (int i = threadIdx.x; i < 16384; i += 256) {
        float4 v = p[i];
        unsigned base = (unsigned)(seg * 65536 + i * 4);
        float vv[4] = {v.x, v.y, v.z, v.w};
#pragma unroll
        for (int d = 0; d < 4; ++d) {
            if (vv[d] >= 0.95f) {
                int b = fbin(vv[d]);
                atomicAdd(&lh[b], 1u);
                if (b >= BINLO && b <= BINHI) {
                    unsigned pos = atomicAdd(&lcnt, 1u);
                    if (pos < LCAP) {
                        lcand[pos].x = __float_as_uint(vv[d]);
                        lcand[pos].y = base + (unsigned)d;
                    }
                }
            }
        }
    }
    __syncthreads();
    unsigned* gh = hist + g * NBINS;
    for (int i = threadIdx.x; i < NBINS; i += 256)
        if (lh[i]) atomicAdd(&gh[i], lh[i]);
    unsigned n = lcnt; if (n > LCAP) n = LCAP;
    if (threadIdx.x == 0) gbase = atomicAdd(&candCount[g], n);
    __syncthreads();
    unsigned gb = gbase;
    uint2* cg = cand + (size_t)g * CAP;
    for (unsigned i = threadIdx.x; i < n; i += 256) {
        unsigned pos = gb + i;
        if (pos < CAP) cg[pos] = lcand[i];
    }
}

// ---- K2: threshold bin + needed count inside it ----
__global__ __launch_bounds__(256) void k_selbin(const unsigned* __restrict__ hist,
                                                unsigned* __restrict__ binSel,
                                                unsigned* __restrict__ needArr) {
    int g = blockIdx.x;
    __shared__ unsigned csum[256];
    __shared__ unsigned after[256];
    const unsigned* gh = hist + g * NBINS;
    int t = threadIdx.x;
    unsigned s = 0;
    for (int i = 0; i < 16; ++i) s += gh[t * 16 + i];
    csum[t] = s;
    __syncthreads();
    if (t == 0) {
        unsigned run = 0;
        for (int c = 255; c >= 0; --c) { after[c] = run; run += csum[c]; }
    }
    __syncthreads();
    if (after[t] < (unsigned)KKEEP && after[t] + csum[t] >= (unsigned)KKEEP) {
        unsigned cum = after[t];
        for (int b2 = t * 16 + 15; b2 >= t * 16; --b2) {
            unsigned h = gh[b2];
            cum += h;
            if (cum >= (unsigned)KKEEP) {
                binSel[g] = (unsigned)b2;
                needArr[g] = (unsigned)KKEEP - (cum - h);
                break;
            }
        }
    }
}

// ---- K3: exact rank within threshold bin -> T + tie index list ----
__global__ __launch_bounds__(256) void k_rank(const uint2* __restrict__ cand,
                                              const unsigned* __restrict__ candCount,
                                              const unsigned* __restrict__ binSel,
                                              const unsigned* __restrict__ needArr,
                                              float* __restrict__ thr,
                                              unsigned* __restrict__ tieIdx,
                                              unsigned* __restrict__ tieCount) {
    int g = blockIdx.x;
    __shared__ uint2 mem[256];
    __shared__ unsigned mb;
    __shared__ float sT;
    unsigned m = candCount[g]; if (m > CAP) m = CAP;
    unsigned bsel = binSel[g];
    unsigned need = needArr[g];
    const uint2* cg = cand + (size_t)g * CAP;
    int t = threadIdx.x;
    if (t == 0) mb = 0;
    __syncthreads();
    for (unsigned ci = t; ci < m; ci += 256) {
        float v = __uint_as_float(cg[ci].x);
        if ((unsigned)fbin(v) == bsel) {
            unsigned i = atomicAdd(&mb, 1u);
            if (i < 256) mem[i] = cg[ci];
        }
    }
    __syncthreads();
    unsigned M = mb; if (M > 256) M = 256;
    unsigned rk = 0; float v = 0.f; unsigned idx = 0;
    if (t < (int)M) {
        v = __uint_as_float(mem[t].x);
        idx = mem[t].y;
        for (unsigned j = 0; j < M; ++j) {
            float vj = __uint_as_float(mem[j].x);
            if (vj > v || (vj == v && mem[j].y < idx)) ++rk;
        }
        if (rk == need - 1) sT = v;
    }
    __syncthreads();
    float T = sT;
    if (t == 0) thr[g] = T;
    if (t < (int)M && v == T && rk < need) {
        unsigned pos = atomicAdd(&tieCount[g], 1u);
        if (pos < TIECAP) tieIdx[g * TIECAP + pos] = idx;
    }
}

__device__ __forceinline__ float keepf(float v, unsigned idx, float T,
                                       const unsigned* __restrict__ tie, unsigned tc) {
    if (v > T) return v;
    if (v == T) {
        for (unsigned i = 0; i < tc; ++i)
            if (tie[i] == idx) return v;
    }
    return 0.f;
}

// ---- K4: masked symmetrize into d_out adj region + deg ----
__global__ __launch_bounds__(256) void k_sym(const float* __restrict__ adj,
                                             const float* __restrict__ thr,
                                             const unsigned* __restrict__ tieIdx,
                                             const unsigned* __restrict__ tieCount,
                                             float* __restrict__ sOut,
                                             float* __restrict__ deg) {
    __shared__ float Al[64 * 65];
    __shared__ float Bl[64 * 65];
    int g = blockIdx.x / 136;
    int pr = blockIdx.x % 136;
    int ti = 0, rem = pr;
    while (rem >= 16 - ti) { rem -= 16 - ti; ++ti; }
    int tj = ti + rem;
    int t = threadIdx.x;
    float T = thr[g];
    unsigned tc = tieCount[g];
    if (tc > TIECAP) tc = TIECAP;
    const unsigned* tie = tieIdx + g * TIECAP;
    const float* ag = adj + (size_t)g * MAT;
    float* sg = sOut + (size_t)g * MAT;
    float* dg = deg + g * NN1;
    int r0 = t >> 4;
    int c0 = (t & 15) << 2;
    int i0 = ti << 6, j0 = tj << 6;
    bool off = (ti != tj);
    float av[4][4], bv[4][4];
#pragma unroll
    for (int q = 0; q < 4; ++q) {
        int r = r0 + (q << 4);
        unsigned base = (unsigned)((i0 + r) * NN1 + j0 + c0);
        float4 v = *(const float4*)(ag + base);
        av[q][0] = keepf(v.x, base + 0, T, tie, tc);
        av[q][1] = keepf(v.y, base + 1, T, tie, tc);
        av[q][2] = keepf(v.z, base + 2, T, tie, tc);
        av[q][3] = keepf(v.w, base + 3, T, tie, tc);
        Al[r * 65 + c0 + 0] = av[q][0];
        Al[r * 65 + c0 + 1] = av[q][1];
        Al[r * 65 + c0 + 2] = av[q][2];
        Al[r * 65 + c0 + 3] = av[q][3];
    }
    if (off) {
#pragma unroll
        for (int q = 0; q < 4; ++q) {
            int r = r0 + (q << 4);
            unsigned base = (unsigned)((j0 + r) * NN1 + i0 + c0);
            float4 v = *(const float4*)(ag + base);
            bv[q][0] = keepf(v.x, base + 0, T, tie, tc);
            bv[q][1] = keepf(v.y, base + 1, T, tie, tc);
            bv[q][2] = keepf(v.z, base + 2, T, tie, tc);
            bv[q][3] = keepf(v.w, base + 3, T, tie, tc);
            Bl[r * 65 + c0 + 0] = bv[q][0];
            Bl[r * 65 + c0 + 1] = bv[q][1];
            Bl[r * 65 + c0 + 2] = bv[q][2];
            Bl[r * 65 + c0 + 3] = bv[q][3];
        }
    }
    __syncthreads();
#pragma unroll
    for (int q = 0; q < 4; ++q) {
        int r = r0 + (q << 4);
        const float* Tr = off ? Bl : Al;
        float s0 = 0.5f * (av[q][0] + Tr[(c0 + 0) * 65 + r]);
        float s1 = 0.5f * (av[q][1] + Tr[(c0 + 1) * 65 + r]);
        float s2 = 0.5f * (av[q][2] + Tr[(c0 + 2) * 65 + r]);
        float s3 = 0.5f * (av[q][3] + Tr[(c0 + 3) * 65 + r]);
        *(float4*)(sg + (size_t)(i0 + r) * NN1 + j0 + c0) = make_float4(s0, s1, s2, s3);
        float rs = s0 + s1 + s2 + s3;
        rs += __shfl_xor(rs, 1);
        rs += __shfl_xor(rs, 2);
        rs += __shfl_xor(rs, 4);
        rs += __shfl_xor(rs, 8);
        if ((t & 15) == 0) atomicAdd(&dg[i0 + r], rs);
    }
    if (off) {
#pragma unroll
        for (int q = 0; q < 4; ++q) {
            int r = r0 + (q << 4);
            float s0 = 0.5f * (bv[q][0] + Al[(c0 + 0) * 65 + r]);
            float s1 = 0.5f * (bv[q][1] + Al[(c0 + 1) * 65 + r]);
            float s2 = 0.5f * (bv[q][2] + Al[(c0 + 2) * 65 + r]);
            float s3 = 0.5f * (bv[q][3] + Al[(c0 + 3) * 65 + r]);
            *(float4*)(sg + (size_t)(j0 + r) * NN1 + i0 + c0) = make_float4(s0, s1, s2, s3);
            float rs = s0 + s1 + s2 + s3;
            rs += __shfl_xor(rs, 1);
            rs += __shfl_xor(rs, 2);
            rs += __shfl_xor(rs, 4);
            rs += __shfl_xor(rs, 8);
            if ((t & 15) == 0) atomicAdd(&dg[j0 + r], rs);
        }
    }
}

// ---- K5: dinv ----
__global__ __launch_bounds__(256) void k_dinv(const float* __restrict__ deg,
                                              float* __restrict__ dinv) {
    int i = blockIdx.x * 256 + threadIdx.x;
    float d = deg[i];
    dinv[i] = (d > 0.f) ? (float)(1.0 / sqrt((double)d)) : 0.f;
}

// ---- K6: y = x @ W, stored transposed (k-major) as bf16 hi/lo splits ----
// Yh/Yl layout: [G][128 c][1024 k]
__global__ __launch_bounds__(256) void k_y(const float* __restrict__ x,
                                           const float* __restrict__ W,
                                           unsigned short* __restrict__ Yh,
                                           unsigned short* __restrict__ Yl) {
    __shared__ float Xl[64 * 128];
    int bx = blockIdx.x;
    int g = bx & 31, chunk = bx >> 5;
    int r0 = chunk * 64;
    int t = threadIdx.x;
    const float* xg = x + ((size_t)g * NN1 + r0) * FF;
    for (int i = t; i < 2048; i += 256) ((float4*)Xl)[i] = ((const float4*)xg)[i];
    __syncthreads();
    int Rr = (t >> 5) * 8;          // 8 rows per thread
    int c4 = (t & 31) * 4;          // 4 cols per thread
    float acc[8][4];
#pragma unroll
    for (int i = 0; i < 8; ++i)
#pragma unroll
        for (int j = 0; j < 4; ++j) acc[i][j] = 0.f;
    for (int f = 0; f < 128; ++f) {
        float4 wv = *(const float4*)(W + (size_t)f * 128 + c4);
#pragma unroll
        for (int i = 0; i < 8; ++i) {
            float a = Xl[(Rr + i) * 128 + f];
            acc[i][0] += a * wv.x;
            acc[i][1] += a * wv.y;
            acc[i][2] += a * wv.z;
            acc[i][3] += a * wv.w;
        }
    }
#pragma unroll
    for (int cc = 0; cc < 4; ++cc) {
        int c = c4 + cc;
        size_t base = ((size_t)g * 128 + c) * NN1 + r0 + Rr;
        ushort8 hh, ll;
#pragma unroll
        for (int i = 0; i < 8; ++i) {
            float v = acc[i][cc];
            unsigned short h = f2bf(v);
            hh[i] = h;
            ll[i] = f2bf(v - bf2f(h));
        }
        *(ushort8*)(Yh + base) = hh;
        *(ushort8*)(Yl + base) = ll;
    }
}

// ---- K7: fused dinv-scale (norm write-back in place) + split-bf16 MFMA GEMM +
//          epilogue h = gelu(y + A_n y + b). 32-row panels, grid 1024, 4 waves. ----
__global__ __launch_bounds__(256) void k_ng1(const unsigned short* __restrict__ Yh,
                                             const unsigned short* __restrict__ Yl,
                                             const float* __restrict__ dinv,
                                             float* __restrict__ sadj,
                                             const float* __restrict__ bias,
                                             float* __restrict__ hout) {
    __shared__ unsigned short AhL[32 * 40];
    __shared__ unsigned short AlL[32 * 40];
    int bx = blockIdx.x;
    int g = bx & 31, panel = bx >> 5;     // same-g blocks share XCD (bx%8 == g%8)
    int r0 = panel * 32;
    int t = threadIdx.x;
    int w = t >> 6, lane = t & 63;
    int q = lane >> 4, n16 = lane & 15;
    float* sg = sadj + (size_t)g * MAT;
    const float* dv = dinv + g * NN1;
    int srow = t >> 3, skc = (t & 7) << 2;     // staging: 32 rows x 32 k
    float drow = dv[r0 + srow];
    int cbase = w * 32;
    const unsigned short* yhg = Yh + (size_t)g * 128 * NN1;
    const unsigned short* ylg = Yl + (size_t)g * 128 * NN1;
    const unsigned short* ybh[2], *ybl[2];
#pragma unroll
    for (int ct = 0; ct < 2; ++ct) {
        size_t co = (size_t)(cbase + 16 * ct + n16) * NN1;
        ybh[ct] = yhg + co;
        ybl[ct] = ylg + co;
    }
    floatx4 acc[2][2];
#pragma unroll
    for (int i = 0; i < 2; ++i)
#pragma unroll
        for (int j = 0; j < 2; ++j) acc[i][j] = (floatx4){0.f, 0.f, 0.f, 0.f};

    for (int kt = 0; kt < 32; ++kt) {
        int k0 = kt << 5;
        // stage + scale + norm write-back + split
        float4 dj = *(const float4*)(dv + k0 + skc);
        float* ap = sg + (size_t)(r0 + srow) * NN1 + k0 + skc;
        float4 v = *(const float4*)ap;
        v.x *= drow * dj.x; v.y *= drow * dj.y;
        v.z *= drow * dj.z; v.w *= drow * dj.w;
        *(float4*)ap = v;
        float vv[4] = {v.x, v.y, v.z, v.w};
        ushort4 hh, ll;
        unsigned short* hp = (unsigned short*)&hh;
        unsigned short* lp = (unsigned short*)&ll;
#pragma unroll
        for (int d = 0; d < 4; ++d) {
            unsigned short h = f2bf(vv[d]);
            hp[d] = h;
            lp[d] = f2bf(vv[d] - bf2f(h));
        }
        *(ushort4*)(&AhL[srow * 40 + skc]) = hh;
        *(ushort4*)(&AlL[srow * 40 + skc]) = ll;
        __syncthreads();
        short8 ah[2], al[2], bh[2], bl[2];
#pragma unroll
        for (int rt = 0; rt < 2; ++rt) {
            ah[rt] = *(const short8*)(&AhL[(16 * rt + n16) * 40 + q * 8]);
            al[rt] = *(const short8*)(&AlL[(16 * rt + n16) * 40 + q * 8]);
        }
#pragma unroll
        for (int ct = 0; ct < 2; ++ct) {
            bh[ct] = *(const short8*)(ybh[ct] + k0 + q * 8);
            bl[ct] = *(const short8*)(ybl[ct] + k0 + q * 8);
        }
#pragma unroll
        for (int rt = 0; rt < 2; ++rt)
#pragma unroll
            for (int ct = 0; ct < 2; ++ct) {
                acc[rt][ct] = __builtin_amdgcn_mfma_f32_16x16x32_bf16(ah[rt], bh[ct], acc[rt][ct], 0, 0, 0);
                acc[rt][ct] = __builtin_amdgcn_mfma_f32_16x16x32_bf16(ah[rt], bl[ct], acc[rt][ct], 0, 0, 0);
                acc[rt][ct] = __builtin_amdgcn_mfma_f32_16x16x32_bf16(al[rt], bh[ct], acc[rt][ct], 0, 0, 0);
            }
        __syncthreads();
    }
    // epilogue: h = gelu(y + agg + b)
    float* hg = hout + (size_t)g * NN1 * FF;
#pragma unroll
    for (int rt = 0; rt < 2; ++rt)
#pragma unroll
        for (int ct = 0; ct < 2; ++ct) {
            int c = cbase + 16 * ct + n16;
            float bb = bias[c];
#pragma unroll
            for (int reg = 0; reg < 4; ++reg) {
                int r = r0 + 16 * rt + 4 * q + reg;
                float yv = bf2f(ybh[ct][r]) + bf2f(ybl[ct][r]);
                float val = acc[rt][ct][reg] + yv + bb;
                hg[(size_t)r * FF + c] = gelu(val);
            }
        }
}

extern "C" void kernel_launch(void* const* d_in, const int* in_sizes, int n_in,
                              void* d_out, int out_size, void* d_ws, size_t ws_size,
                              hipStream_t stream) {
    const float* x = (const float*)d_in[0];
    const float* adj = (const float*)d_in[1];
    const float* W = (const float*)d_in[2];
    const float* b = (const float*)d_in[3];
    float* out = (float*)d_out;
    float* hout = out;                            // [G*N, 128]
    float* adjn = out + (size_t)GG * NN1 * FF;    // [G, N, N]

    char* ws = (char*)d_ws;
    unsigned* hist      = (unsigned*)(ws);                 // 524288
    unsigned* candCount = (unsigned*)(ws + 524288);        // 128
    unsigned* tieCount  = (unsigned*)(ws + 524416);        // 128
    float*    deg       = (float*)(ws + 524544);           // 131072 -> 655616
    unsigned* binSel    = (unsigned*)(ws + 655616);        // 128
    unsigned* needArr   = (unsigned*)(ws + 655744);        // 128
    float*    thr       = (float*)(ws + 655872);           // 128
    unsigned* tieIdx    = (unsigned*)(ws + 656000);        // 8192 -> 664192
    uint2*    cand      = (uint2*)(ws + 664192);           // 2097152 -> 2761344
    float*    dinv      = (float*)(ws + 2761344);          // 131072 -> 2892416
    unsigned short* Yh  = (unsigned short*)(ws + 2892416); // 8388608 -> 11281024
    unsigned short* Yl  = (unsigned short*)(ws + 11281024);// 8388608 -> 19669632

    hipMemsetAsync(d_ws, 0, 655616, stream);   // hist + counts + deg

    k_histgather<<<512, 256, 0, stream>>>(adj, hist, cand, candCount);
    k_selbin<<<32, 256, 0, stream>>>(hist, binSel, needArr);
    k_rank<<<32, 256, 0, stream>>>(cand, candCount, binSel, needArr, thr, tieIdx, tieCount);
    k_sym<<<GG * 136, 256, 0, stream>>>(adj, thr, tieIdx, tieCount, adjn, deg);
    k_dinv<<<128, 256, 0, stream>>>(deg, dinv);
    k_y<<<512, 256, 0, stream>>>(x, W, Yh, Yl);
    k_ng1<<<1024, 256, 0, stream>>>(Yh, Yl, dinv, adjn, b, hout);
}